// Round 9
// baseline (152.385 us; speedup 1.0000x reference)
//
#include <hip/hip_runtime.h>
#include <hip/hip_fp16.h>

// B=8, T=S=512, M=N=512, H=128
// score[b,t,s] = (1/sqrt(512)) * sum_h v[h]*tanh(x1[b,t,h]+x2[b,s,h])
// tanh(x) = 1 - 2/(1+e^{2x}) => score = (Sv - 2*sum_h v_h*sigma_h)/SCALE,
//   sigma = 1/(1+e), e = exp2(z1+z2), z_i = 2*log2(e)*x_i (z stored f32).
// Round-9:
//  * proj: register-prefetch pipeline (T14 async-stage): next K-tile's 5
//    global float4 loads issue right after the post-stage barrier and are
//    consumed at the next loop head -> HBM latency hides under the FMA
//    phase. Attacks the serialized stage->barrier->compute structure shared
//    by all four invariant ~36us proj variants.
//  * score: r7 geometry (best measured 57.7us: 512thr, 64x64 tile, 2t x 4s,
//    v2f pk math) with h-group widened to 8 and an 8-way rcp merge along h.
//    Clamp tightened z<=14 so den = prod of 8 (e+1) <= 2^112 stays finite
//    (sigma error from clamp <= 6e-5/elem, far below threshold).

constexpr float SCALE_IN  = 2.8853900817779268f;   // 2*log2(e)
constexpr float INV_SCALE = 0.04419417382415922f;  // 1/sqrt(512)

typedef float v2f __attribute__((ext_vector_type(2)));

__device__ __forceinline__ v2f exp2v(v2f z) {
  v2f r;
  r.x = __builtin_amdgcn_exp2f(z.x);
  r.y = __builtin_amdgcn_exp2f(z.y);
  return r;
}
__device__ __forceinline__ v2f rcpv(v2f d) {
  v2f r;
  r.x = __builtin_amdgcn_rcpf(d.x);
  r.y = __builtin_amdgcn_rcpf(d.y);
  return r;
}

// ---------------- Projection GEMM -> z planes (register-prefetch) ------------
// Grid 256 blocks (128 per matrix), 512 threads. Block: 32 rows x 128 h.
// LDS: A 32x64 (8KB) + W 64x128 (32KB). Thread: 2r x 4h.
// Pipeline per K-tile: {ds_write staged regs; barrier; issue next-tile
// global loads; FMA over 64 k; barrier}.
__global__ __launch_bounds__(512) void proj_kernel(
    const float* __restrict__ q,  const float* __restrict__ w2,
    const float* __restrict__ ky, const float* __restrict__ w1,
    float* __restrict__ x1z, float* __restrict__ x2z) {
  __shared__ float As[32 * 64];    // [row][k]
  __shared__ float Ws[64 * 128];   // [k][h]

  int blk = blockIdx.x;
  const float* A; const float* W; float* O;
  if (blk < 128) { A = q;  W = w2; O = x1z; }
  else           { blk -= 128; A = ky; W = w1; O = x2z; }
  const int rbase = blk * 32;
  const int tid = threadIdx.x;

  const int rq = tid >> 5;          // 0..15 -> rows 2*rq+{0,1}
  const int hq = tid & 31;          // h = 4*hq+{0..3}

  float acc[2][4];
#pragma unroll
  for (int r = 0; r < 2; ++r)
#pragma unroll
    for (int c = 0; c < 4; ++c) acc[r][c] = 0.0f;

  const int arow = tid >> 4;          // 0..31
  const int kq4  = (tid & 15) * 4;
  const int wrow = tid >> 5;          // 0..15
  const int wg   = (tid & 31) * 4;

  const float* Abase = A + (size_t)(rbase + arow) * 512 + kq4;
  const float* Wbase = W + (size_t)wrow * 128 + wg;

  // prologue: stage tile 0 into registers
  float4 areg = *(const float4*)(Abase);
  float4 wreg[4];
#pragma unroll
  for (int p = 0; p < 4; ++p)
    wreg[p] = *(const float4*)(Wbase + (size_t)(16 * p) * 128);

  for (int kb = 0; kb < 512; kb += 64) {
    // regs -> LDS (vmcnt wait lands here; hidden by previous compute)
    *(float4*)(As + arow * 64 + kq4) = areg;
#pragma unroll
    for (int p = 0; p < 4; ++p)
      *(float4*)(Ws + (wrow + 16 * p) * 128 + wg) = wreg[p];
    __syncthreads();

    // issue next tile's global loads; latency hides under the FMA loop
    if (kb < 448) {
      areg = *(const float4*)(Abase + kb + 64);
#pragma unroll
      for (int p = 0; p < 4; ++p)
        wreg[p] =
            *(const float4*)(Wbase + (size_t)(kb + 64 + 16 * p) * 128);
    }

#pragma unroll 4
    for (int k4 = 0; k4 < 64; k4 += 4) {
      float a[2][4], w[4][4];
      *(float4*)a[0] = *(const float4*)(As + (2 * rq + 0) * 64 + k4);
      *(float4*)a[1] = *(const float4*)(As + (2 * rq + 1) * 64 + k4);
#pragma unroll
      for (int kk = 0; kk < 4; ++kk)
        *(float4*)w[kk] = *(const float4*)(Ws + (k4 + kk) * 128 + 4 * hq);
#pragma unroll
      for (int kk = 0; kk < 4; ++kk)
#pragma unroll
        for (int r = 0; r < 2; ++r)
#pragma unroll
          for (int c = 0; c < 4; ++c)
            acc[r][c] = fmaf(a[r][kk], w[kk][c], acc[r][c]);
    }
    __syncthreads();   // compute done; LDS may be overwritten next iter
  }

#pragma unroll
  for (int r = 0; r < 2; ++r) {
    float4 z;
    z.x = acc[r][0] * SCALE_IN;
    z.y = acc[r][1] * SCALE_IN;
    z.z = acc[r][2] * SCALE_IN;
    z.w = acc[r][3] * SCALE_IN;
    *(float4*)(O + (size_t)(rbase + 2 * rq + r) * 128 + 4 * hq) = z;
  }
}

// ---------------- Main score kernel (r7 geometry, 8-way h merge) -------------
// 512 blocks x 512 threads. Tile 64(t) x 64(s), H in two 64-h phases.
// LDS 32KB ([64h][64t] + [64h][64s] f32). Thread: 2t x 4s (2 v2f s-pairs).
// Per 8h x 2s unit: 8 pk_add + 8 pk_min + 16 exp2 + 8 pk_add1 + product
// tree (7 pk_mul) + 8 pk u-terms + 6 pk num-tree + 2 rcp + 1 pk_fma.
__global__ __launch_bounds__(512, 4) void score_kernel(
    const float* __restrict__ x1z, const float* __restrict__ x2z,
    const float* __restrict__ v, float* __restrict__ out) {
  __shared__ float x1l[64 * 64];  // [h(64)][t(64)] 16KB
  __shared__ float x2l[64 * 64];  // [h(64)][s(64)] 16KB

  const int tid   = threadIdx.x;
  const int b     = blockIdx.x >> 6;
  const int tile  = blockIdx.x & 63;
  const int tbase = (tile >> 3) * 64;    // 8 t-tiles
  const int sbase = (tile & 7) * 64;     // 8 s-tiles

  const float* x1g = x1z + (size_t)(b * 512 + tbase) * 128;
  const float* x2g = x2z + (size_t)(b * 512 + sbase) * 128;

  const int sg = tid & 15;   // s = 4*sg+j (coalesced float4 stores)
  const int tg = tid >> 4;   // 0..31, t = 2*tg+i

  v2f racc[2][2];
#pragma unroll
  for (int i = 0; i < 2; ++i)
#pragma unroll
    for (int jp = 0; jp < 2; ++jp) racc[i][jp] = (v2f){0.0f, 0.0f};
  float sv = 0.0f;

  const v2f C14 = {14.0f, 14.0f};

  for (int ph = 0; ph < 2; ++ph) {
    // transposed staging: [row][h] global -> [h][row] LDS. 2-way banks, free.
    {
      const int r1 = tid & 63;            // row within tile
      const int c0 = tid >> 6;            // 0..7
#pragma unroll
      for (int p = 0; p < 2; ++p) {
        const int c = c0 + 8 * p;         // 0..15 -> h = 4c..4c+3
        const float4 a =
            *(const float4*)(x1g + (size_t)r1 * 128 + ph * 64 + 4 * c);
        x1l[(4 * c + 0) * 64 + r1] = a.x;
        x1l[(4 * c + 1) * 64 + r1] = a.y;
        x1l[(4 * c + 2) * 64 + r1] = a.z;
        x1l[(4 * c + 3) * 64 + r1] = a.w;
        const float4 s =
            *(const float4*)(x2g + (size_t)r1 * 128 + ph * 64 + 4 * c);
        x2l[(4 * c + 0) * 64 + r1] = s.x;
        x2l[(4 * c + 1) * 64 + r1] = s.y;
        x2l[(4 * c + 2) * 64 + r1] = s.z;
        x2l[(4 * c + 3) * 64 + r1] = s.w;
      }
    }
    __syncthreads();

    for (int hg = 0; hg < 8; ++hg) {
      const int h0 = hg * 8;
      const float4 vq0 = *(const float4*)(v + ph * 64 + h0);      // uniform
      const float4 vq1 = *(const float4*)(v + ph * 64 + h0 + 4);  // uniform
      sv += (vq0.x + vq0.y) + (vq0.z + vq0.w) +
            (vq1.x + vq1.y) + (vq1.z + vq1.w);

      float zt[2][8];    // [i][qq]
      v2f   zs[2][8];    // [jp][qq], s-pair packed
#pragma unroll
      for (int qq = 0; qq < 8; ++qq) {
        const float2 tp = *(const float2*)(x1l + (h0 + qq) * 64 + 2 * tg);
        zt[0][qq] = tp.x;
        zt[1][qq] = tp.y;
        const float4 sp = *(const float4*)(x2l + (h0 + qq) * 64 + 4 * sg);
        zs[0][qq] = (v2f){sp.x, sp.y};
        zs[1][qq] = (v2f){sp.z, sp.w};
      }

#pragma unroll
      for (int i = 0; i < 2; ++i) {
#pragma unroll
        for (int jp = 0; jp < 2; ++jp) {
          v2f A[8];
#pragma unroll
          for (int qq = 0; qq < 8; ++qq) {
            const v2f e =
                exp2v(__builtin_elementwise_min(zt[i][qq] + zs[jp][qq], C14));
            A[qq] = e + 1.0f;              // A in [1, 2^14+1]
          }
          const v2f P01 = A[0] * A[1], P23 = A[2] * A[3];
          const v2f P45 = A[4] * A[5], P67 = A[6] * A[7];
          const v2f P0123 = P01 * P23, P4567 = P45 * P67;
          const v2f D = P0123 * P4567;     // <= 2^112, finite
          const v2f u01 = vq0.x * A[1] + vq0.y * A[0];
          const v2f u23 = vq0.z * A[3] + vq0.w * A[2];
          const v2f u45 = vq1.x * A[5] + vq1.y * A[4];
          const v2f u67 = vq1.z * A[7] + vq1.w * A[6];
          const v2f n0123 = u01 * P23 + u23 * P01;
          const v2f n4567 = u45 * P67 + u67 * P45;
          const v2f NUM = n0123 * P4567 + n4567 * P0123;   // <= ~2^101
          racc[i][jp] += NUM * rcpv(D);
        }
      }
    }
    __syncthreads();   // before next phase overwrites LDS
  }

  const float c1v = sv * INV_SCALE;
  const float c2v = -2.0f * INV_SCALE;
#pragma unroll
  for (int i = 0; i < 2; ++i) {
    const int t = tbase + 2 * tg + i;
    float4 o;
    o.x = fmaf(racc[i][0].x, c2v, c1v);
    o.y = fmaf(racc[i][0].y, c2v, c1v);
    o.z = fmaf(racc[i][1].x, c2v, c1v);
    o.w = fmaf(racc[i][1].y, c2v, c1v);
    *(float4*)(out + (size_t)(b * 512 + t) * 512 + sbase + 4 * sg) = o;
  }
}

extern "C" void kernel_launch(void* const* d_in, const int* in_sizes, int n_in,
                              void* d_out, int out_size, void* d_ws, size_t ws_size,
                              hipStream_t stream) {
  const float* query = (const float*)d_in[0];  // (8,512,512)
  const float* keys  = (const float*)d_in[1];  // (8,512,512)
  const float* W1    = (const float*)d_in[2];  // (512,128) pairs with keys
  const float* W2    = (const float*)d_in[3];  // (512,128) pairs with query
  const float* v     = (const float*)d_in[4];  // (128,)
  float* out = (float*)d_out;                  // (8,512,512) fp32

  float* x1zp = (float*)d_ws;                  // 8*512*128 f32 (2 MB)
  float* x2zp = x1zp + 8 * 512 * 128;          // 2 MB more

  hipLaunchKernelGGL(proj_kernel, dim3(256), dim3(512), 0, stream,
                     query, W2, keys, W1, x1zp, x2zp);
  hipLaunchKernelGGL(score_kernel, dim3(512), dim3(512), 0, stream,
                     x1zp, x2zp, v, out);
}

// Round 10
// 137.171 us; speedup vs baseline: 1.1109x; 1.1109x over previous
//
#include <hip/hip_runtime.h>
#include <hip/hip_fp16.h>

// B=8, T=S=512, M=N=512, H=128
// score[b,t,s] = (1/sqrt(512)) * sum_h v[h]*tanh(x1[b,t,h]+x2[b,s,h])
// tanh(x) = 1 - 2/(1+e^{2x}) => score = (Sv - 2*sum_h v_h*sigma_h)/SCALE,
//   sigma = 1/(1+e), e = exp2(z1+z2), z_i = 2*log2(e)*x_i (z stored f32).
// Round-10: recombination of proven-best halves.
//  * proj: r7's simple staged full-K kernel (register-prefetch r9 variant
//    REGRESSED proj ~36 -> ~50us; all three latency-hiding attempts null or
//    negative -> proj is at its LDS-read geometric floor: 3 B/FMA given
//    grid>=256, 512thr, 8-output thread tiles).
//  * score: r9's 8-way h-merge (best measured 55.9us; ladder 64.5 -> 60.6
//    -> 57.7 -> 55.9 across formulations). z clamp 14 -> den <= 2^112.

constexpr float SCALE_IN  = 2.8853900817779268f;   // 2*log2(e)
constexpr float INV_SCALE = 0.04419417382415922f;  // 1/sqrt(512)

typedef float v2f __attribute__((ext_vector_type(2)));

__device__ __forceinline__ v2f exp2v(v2f z) {
  v2f r;
  r.x = __builtin_amdgcn_exp2f(z.x);
  r.y = __builtin_amdgcn_exp2f(z.y);
  return r;
}
__device__ __forceinline__ v2f rcpv(v2f d) {
  v2f r;
  r.x = __builtin_amdgcn_rcpf(d.x);
  r.y = __builtin_amdgcn_rcpf(d.y);
  return r;
}

// ---------------- Projection GEMM -> z planes (r7-verified) ------------------
// Fused full-K: grid 256 blocks (128 per matrix), 512 threads. Block:
// 32 rows x 128 h. LDS: A 32x64 (8KB) + W 64x128 (32KB). Thread: 2r x 4h.
__global__ __launch_bounds__(512) void proj_kernel(
    const float* __restrict__ q,  const float* __restrict__ w2,
    const float* __restrict__ ky, const float* __restrict__ w1,
    float* __restrict__ x1z, float* __restrict__ x2z) {
  __shared__ float As[32 * 64];    // [row][k]
  __shared__ float Ws[64 * 128];   // [k][h]

  int blk = blockIdx.x;
  const float* A; const float* W; float* O;
  if (blk < 128) { A = q;  W = w2; O = x1z; }
  else           { blk -= 128; A = ky; W = w1; O = x2z; }
  const int rbase = blk * 32;
  const int tid = threadIdx.x;

  const int rq = tid >> 5;          // 0..15 -> rows 2*rq+{0,1}
  const int hq = tid & 31;          // h = 4*hq+{0..3}

  float acc[2][4];
#pragma unroll
  for (int r = 0; r < 2; ++r)
#pragma unroll
    for (int c = 0; c < 4; ++c) acc[r][c] = 0.0f;

  for (int kb = 0; kb < 512; kb += 64) {
    {
      const int arow = tid >> 4;          // 0..31
      const int kq4  = (tid & 15) * 4;
      *(float4*)(As + arow * 64 + kq4) =
          *(const float4*)(A + (size_t)(rbase + arow) * 512 + kb + kq4);
      const int wrow = tid >> 5;          // 0..15
      const int hq4  = (tid & 31) * 4;
#pragma unroll
      for (int p = 0; p < 4; ++p)
        *(float4*)(Ws + (wrow + 16 * p) * 128 + hq4) =
            *(const float4*)(W + (size_t)(kb + wrow + 16 * p) * 128 + hq4);
    }
    __syncthreads();
#pragma unroll 4
    for (int k4 = 0; k4 < 64; k4 += 4) {
      float a[2][4], w[4][4];
      *(float4*)a[0] = *(const float4*)(As + (2 * rq + 0) * 64 + k4);
      *(float4*)a[1] = *(const float4*)(As + (2 * rq + 1) * 64 + k4);
#pragma unroll
      for (int kk = 0; kk < 4; ++kk)
        *(float4*)w[kk] = *(const float4*)(Ws + (k4 + kk) * 128 + 4 * hq);
#pragma unroll
      for (int kk = 0; kk < 4; ++kk)
#pragma unroll
        for (int r = 0; r < 2; ++r)
#pragma unroll
          for (int c = 0; c < 4; ++c)
            acc[r][c] = fmaf(a[r][kk], w[kk][c], acc[r][c]);
    }
    __syncthreads();
  }

#pragma unroll
  for (int r = 0; r < 2; ++r) {
    float4 z;
    z.x = acc[r][0] * SCALE_IN;
    z.y = acc[r][1] * SCALE_IN;
    z.z = acc[r][2] * SCALE_IN;
    z.w = acc[r][3] * SCALE_IN;
    *(float4*)(O + (size_t)(rbase + 2 * rq + r) * 128 + 4 * hq) = z;
  }
}

// ---------------- Main score kernel (r9-verified: 8-way h merge) -------------
// 512 blocks x 512 threads. Tile 64(t) x 64(s), H in two 64-h phases.
// LDS 32KB ([64h][64t] + [64h][64s] f32). Thread: 2t x 4s (2 v2f s-pairs).
__global__ __launch_bounds__(512, 4) void score_kernel(
    const float* __restrict__ x1z, const float* __restrict__ x2z,
    const float* __restrict__ v, float* __restrict__ out) {
  __shared__ float x1l[64 * 64];  // [h(64)][t(64)] 16KB
  __shared__ float x2l[64 * 64];  // [h(64)][s(64)] 16KB

  const int tid   = threadIdx.x;
  const int b     = blockIdx.x >> 6;
  const int tile  = blockIdx.x & 63;
  const int tbase = (tile >> 3) * 64;    // 8 t-tiles
  const int sbase = (tile & 7) * 64;     // 8 s-tiles

  const float* x1g = x1z + (size_t)(b * 512 + tbase) * 128;
  const float* x2g = x2z + (size_t)(b * 512 + sbase) * 128;

  const int sg = tid & 15;   // s = 4*sg+j (coalesced float4 stores)
  const int tg = tid >> 4;   // 0..31, t = 2*tg+i

  v2f racc[2][2];
#pragma unroll
  for (int i = 0; i < 2; ++i)
#pragma unroll
    for (int jp = 0; jp < 2; ++jp) racc[i][jp] = (v2f){0.0f, 0.0f};
  float sv = 0.0f;

  const v2f C14 = {14.0f, 14.0f};

  for (int ph = 0; ph < 2; ++ph) {
    // transposed staging: [row][h] global -> [h][row] LDS. 2-way banks, free.
    {
      const int r1 = tid & 63;            // row within tile
      const int c0 = tid >> 6;            // 0..7
#pragma unroll
      for (int p = 0; p < 2; ++p) {
        const int c = c0 + 8 * p;         // 0..15 -> h = 4c..4c+3
        const float4 a =
            *(const float4*)(x1g + (size_t)r1 * 128 + ph * 64 + 4 * c);
        x1l[(4 * c + 0) * 64 + r1] = a.x;
        x1l[(4 * c + 1) * 64 + r1] = a.y;
        x1l[(4 * c + 2) * 64 + r1] = a.z;
        x1l[(4 * c + 3) * 64 + r1] = a.w;
        const float4 s =
            *(const float4*)(x2g + (size_t)r1 * 128 + ph * 64 + 4 * c);
        x2l[(4 * c + 0) * 64 + r1] = s.x;
        x2l[(4 * c + 1) * 64 + r1] = s.y;
        x2l[(4 * c + 2) * 64 + r1] = s.z;
        x2l[(4 * c + 3) * 64 + r1] = s.w;
      }
    }
    __syncthreads();

    for (int hg = 0; hg < 8; ++hg) {
      const int h0 = hg * 8;
      const float4 vq0 = *(const float4*)(v + ph * 64 + h0);      // uniform
      const float4 vq1 = *(const float4*)(v + ph * 64 + h0 + 4);  // uniform
      sv += (vq0.x + vq0.y) + (vq0.z + vq0.w) +
            (vq1.x + vq1.y) + (vq1.z + vq1.w);

      float zt[2][8];    // [i][qq]
      v2f   zs[2][8];    // [jp][qq], s-pair packed
#pragma unroll
      for (int qq = 0; qq < 8; ++qq) {
        const float2 tp = *(const float2*)(x1l + (h0 + qq) * 64 + 2 * tg);
        zt[0][qq] = tp.x;
        zt[1][qq] = tp.y;
        const float4 sp = *(const float4*)(x2l + (h0 + qq) * 64 + 4 * sg);
        zs[0][qq] = (v2f){sp.x, sp.y};
        zs[1][qq] = (v2f){sp.z, sp.w};
      }

#pragma unroll
      for (int i = 0; i < 2; ++i) {
#pragma unroll
        for (int jp = 0; jp < 2; ++jp) {
          v2f A[8];
#pragma unroll
          for (int qq = 0; qq < 8; ++qq) {
            const v2f e =
                exp2v(__builtin_elementwise_min(zt[i][qq] + zs[jp][qq], C14));
            A[qq] = e + 1.0f;              // A in [1, 2^14+1]
          }
          const v2f P01 = A[0] * A[1], P23 = A[2] * A[3];
          const v2f P45 = A[4] * A[5], P67 = A[6] * A[7];
          const v2f P0123 = P01 * P23, P4567 = P45 * P67;
          const v2f D = P0123 * P4567;     // <= 2^112, finite
          const v2f u01 = vq0.x * A[1] + vq0.y * A[0];
          const v2f u23 = vq0.z * A[3] + vq0.w * A[2];
          const v2f u45 = vq1.x * A[5] + vq1.y * A[4];
          const v2f u67 = vq1.z * A[7] + vq1.w * A[6];
          const v2f n0123 = u01 * P23 + u23 * P01;
          const v2f n4567 = u45 * P67 + u67 * P45;
          const v2f NUM = n0123 * P4567 + n4567 * P0123;   // <= ~2^101
          racc[i][jp] += NUM * rcpv(D);
        }
      }
    }
    __syncthreads();   // before next phase overwrites LDS
  }

  const float c1v = sv * INV_SCALE;
  const float c2v = -2.0f * INV_SCALE;
#pragma unroll
  for (int i = 0; i < 2; ++i) {
    const int t = tbase + 2 * tg + i;
    float4 o;
    o.x = fmaf(racc[i][0].x, c2v, c1v);
    o.y = fmaf(racc[i][0].y, c2v, c1v);
    o.z = fmaf(racc[i][1].x, c2v, c1v);
    o.w = fmaf(racc[i][1].y, c2v, c1v);
    *(float4*)(out + (size_t)(b * 512 + t) * 512 + sbase + 4 * sg) = o;
  }
}

extern "C" void kernel_launch(void* const* d_in, const int* in_sizes, int n_in,
                              void* d_out, int out_size, void* d_ws, size_t ws_size,
                              hipStream_t stream) {
  const float* query = (const float*)d_in[0];  // (8,512,512)
  const float* keys  = (const float*)d_in[1];  // (8,512,512)
  const float* W1    = (const float*)d_in[2];  // (512,128) pairs with keys
  const float* W2    = (const float*)d_in[3];  // (512,128) pairs with query
  const float* v     = (const float*)d_in[4];  // (128,)
  float* out = (float*)d_out;                  // (8,512,512) fp32

  float* x1zp = (float*)d_ws;                  // 8*512*128 f32 (2 MB)
  float* x2zp = x1zp + 8 * 512 * 128;          // 2 MB more

  hipLaunchKernelGGL(proj_kernel, dim3(256), dim3(512), 0, stream,
                     query, W2, keys, W1, x1zp, x2zp);
  hipLaunchKernelGGL(score_kernel, dim3(512), dim3(512), 0, stream,
                     x1zp, x2zp, v, out);
}